// Round 9
// baseline (1186.958 us; speedup 1.0000x reference)
//
#include <hip/hip_runtime.h>
#include <math.h>

#define N_PIX 16384
#define EMB 128
#define LN_EPS 1e-5f
#define INV_TEMP 10.0f
#define C2 14.4269504f          // INV_TEMP * log2(e): logits in log2 units
#define THR2 26.0f              // skip threshold (log2 units) ~= 18 nats
#define BKT 32
#define NTILES (N_PIX / BKT)    // 512

typedef __attribute__((ext_vector_type(8))) short short8v;
typedef __attribute__((ext_vector_type(4))) float f32x4;

__device__ __forceinline__ float fexp2(float x) {
#if __has_builtin(__builtin_amdgcn_exp2f)
    return __builtin_amdgcn_exp2f(x);
#else
    float r; asm("v_exp_f32 %0, %1" : "=v"(r) : "v"(x)); return r;
#endif
}

__device__ __forceinline__ unsigned cvt_pk_bf16(float lo, float hi) {
    unsigned r;
    asm("v_cvt_pk_bf16_f32 %0, %1, %2" : "=v"(r) : "v"(lo), "v"(hi));
    return r;
}

__device__ __forceinline__ void split_bf16(float x, unsigned short& h, unsigned short& l) {
    union { float f; unsigned u; } a; a.f = x;
    h = (unsigned short)(a.u >> 16);
    union { unsigned u; float f; } b; b.u = a.u & 0xFFFF0000u;
    float r = x - b.f;
    union { float f; unsigned u; } c; c.f = r;
    unsigned ru = c.u + 0x7FFFu + ((c.u >> 16) & 1u);
    l = (unsigned short)(ru >> 16);
}

// ---------------------------------------------------------------------------
// Kernel 1: descriptor + MLP(6->128) + LN + MLP(128->128); emits bf16 hi/lo
// ---------------------------------------------------------------------------
__global__ __launch_bounds__(128) void encode_kernel(
    const float* __restrict__ ego_cls, const float* __restrict__ ego_reg,
    const float* __restrict__ other_cls, const float* __restrict__ other_reg,
    const float* __restrict__ w1, const float* __restrict__ b1,
    const float* __restrict__ ln_g, const float* __restrict__ ln_b,
    const float* __restrict__ w2, const float* __restrict__ b2,
    unsigned short* __restrict__ q_hi, unsigned short* __restrict__ q_lo,
    unsigned short* __restrict__ k_hi, unsigned short* __restrict__ k_lo)
{
    int r = blockIdx.x;
    const float* cls; const float* reg; unsigned short *ohi, *olo; int p;
    if (r < N_PIX) { cls = ego_cls;   reg = ego_reg;   ohi = q_hi; olo = q_lo; p = r; }
    else           { cls = other_cls; reg = other_reg; ohi = k_hi; olo = k_lo; p = r - N_PIX; }

    int j = threadIdx.x;

    float x0 = reg[3*N_PIX + p];
    float x1 = reg[4*N_PIX + p];
    float x2 = reg[5*N_PIX + p];
    float th = reg[6*N_PIX + p];
    float x3 = sinf(th);
    float x4 = cosf(th);
    float x5 = fmaxf(cls[p], cls[N_PIX + p]);

    float h = x0*w1[0*EMB+j] + x1*w1[1*EMB+j] + x2*w1[2*EMB+j]
            + x3*w1[3*EMB+j] + x4*w1[4*EMB+j] + x5*w1[5*EMB+j] + b1[j];
    h = fmaxf(h, 0.f);

    __shared__ float hn[EMB];
    __shared__ float red[4];

    float s = h, s2 = h*h;
    #pragma unroll
    for (int off = 32; off >= 1; off >>= 1) {
        s  += __shfl_xor(s,  off);
        s2 += __shfl_xor(s2, off);
    }
    int wid = j >> 6;
    if ((j & 63) == 0) { red[wid] = s; red[2+wid] = s2; }
    __syncthreads();
    float tot  = red[0] + red[1];
    float tot2 = red[2] + red[3];
    float mu  = tot * (1.f/EMB);
    float var = tot2 * (1.f/EMB) - mu*mu;
    float rstd = rsqrtf(var + LN_EPS);
    float hnj = (h - mu) * rstd * ln_g[j] + ln_b[j];
    hn[j] = hnj;
    __syncthreads();

    float acc = b2[j];
    #pragma unroll 8
    for (int k = 0; k < EMB; ++k)
        acc += hn[k] * w2[k*EMB + j];

    unsigned short hb, lb;
    split_bf16(acc, hb, lb);
    ohi[(size_t)p * EMB + j] = hb;
    olo[(size_t)p * EMB + j] = lb;
}

// ---------------------------------------------------------------------------
// Kernel 2: split-K flash attention, BARRIER-FREE / LDS-FREE.
// Each wave = independent flash unit for 16 queries. K fragments read
// per-lane directly from global (L2-resident slice); all waits
// compiler-managed. Frag map identical to R6's proven bijection:
// element k = kk*32 + lg*8 + e on both A (K rows) and B (Q cols).
// ---------------------------------------------------------------------------
__global__ __launch_bounds__(256, 6) void attn_kernel(
    const unsigned short* __restrict__ Qhi, const unsigned short* __restrict__ Qlo,
    const unsigned short* __restrict__ Khi, const unsigned short* __restrict__ Klo,
    const float* __restrict__ other_cls, const float* __restrict__ other_reg,
    float* __restrict__ macc, float* __restrict__ mbuf, float* __restrict__ lbuf,
    float* __restrict__ out, int S, int TPS, int XPS, int direct)
{
    const int tid  = threadIdx.x;
    const int w    = tid >> 6, lane = tid & 63;
    const int lg   = lane >> 4, lk = lane & 15;

    // XCD-grouped bijective decode: slice pinned per XCD (K-slice L2-resident)
    const int b  = blockIdx.x;
    const int s  = (b & 7) / XPS;
    const int qb = (b >> 3) * XPS + (b & 7) % XPS;
    const int qt0 = qb * 64 + w * 16;
    const int t0  = s * TPS;

    // ---- Q B-operand frags (k-map: k = kk*32 + lg*8 + e) ----
    short8v qbh[4], qbl[4];
    {
        const unsigned short* qh = Qhi + (size_t)(qt0 + lk) * EMB + lg*8;
        const unsigned short* ql = Qlo + (size_t)(qt0 + lk) * EMB + lg*8;
        #pragma unroll
        for (int kk = 0; kk < 4; ++kk) {
            qbh[kk] = *(const short8v*)(qh + kk*32);
            qbl[kk] = *(const short8v*)(ql + kk*32);
        }
    }

    // per-lane K row offsets (element units): key rows lk and 16+lk
    const size_t rowA = (size_t)lk * EMB + lg*8;
    const size_t rowB = (size_t)(16 + lk) * EMB + lg*8;

    const float* vplane = (lk < 2) ? (other_cls + lk * N_PIX)
                                   : (other_reg + (lk - 2) * N_PIX);

    float mrow = -INFINITY, lrow = 0.f;   // mrow in log2 units
    f32x4 accv = {0.f, 0.f, 0.f, 0.f};

    for (int tt = 0; tt < TPS; ++tt) {
        const int kb0 = (t0 + tt) * BKT;
        const size_t tbase = (size_t)kb0 * EMB;
        const unsigned short* h0 = Khi + tbase + rowA;
        const unsigned short* h1 = Khi + tbase + rowB;

        // ---- hi*hi pass: S[key][query] ----
        f32x4 S0 = {0,0,0,0}, S1 = {0,0,0,0};
        #pragma unroll
        for (int kk = 0; kk < 4; ++kk) {
            short8v ah0 = *(const short8v*)(h0 + kk*32);
            short8v ah1 = *(const short8v*)(h1 + kk*32);
            S0 = __builtin_amdgcn_mfma_f32_16x16x32_bf16(ah0, qbh[kk], S0, 0, 0, 0);
            S1 = __builtin_amdgcn_mfma_f32_16x16x32_bf16(ah1, qbh[kk], S1, 0, 0, 0);
        }

        // ---- approx per-query tile max -> wave-uniform skip ----
        float mt = fmaxf(fmaxf(fmaxf(S0[0], S0[1]), fmaxf(S0[2], S0[3])),
                         fmaxf(fmaxf(S1[0], S1[1]), fmaxf(S1[2], S1[3])));
        mt = fmaxf(mt, __shfl_xor(mt, 16));
        mt = fmaxf(mt, __shfl_xor(mt, 32));
        if (__any(mt * C2 > mrow - THR2)) {
            // V loads for this tile (taken tiles only)
            float vt[8];
            #pragma unroll
            for (int e = 0; e < 8; ++e)
                vt[e] = vplane[kb0 + 16*(e>>2) + lg*4 + (e&3)];

            const unsigned short* l0 = Klo + tbase + rowA;
            const unsigned short* l1 = Klo + tbase + rowB;

            // ---- cross terms: + kh*ql + kl*qh (hi frags reload: L1-hot) ----
            #pragma unroll
            for (int kk = 0; kk < 4; ++kk) {
                short8v ah0 = *(const short8v*)(h0 + kk*32);
                short8v ah1 = *(const short8v*)(h1 + kk*32);
                short8v al0 = *(const short8v*)(l0 + kk*32);
                short8v al1 = *(const short8v*)(l1 + kk*32);
                S0 = __builtin_amdgcn_mfma_f32_16x16x32_bf16(ah0, qbl[kk], S0, 0, 0, 0);
                S1 = __builtin_amdgcn_mfma_f32_16x16x32_bf16(ah1, qbl[kk], S1, 0, 0, 0);
                S0 = __builtin_amdgcn_mfma_f32_16x16x32_bf16(al0, qbh[kk], S0, 0, 0, 0);
                S1 = __builtin_amdgcn_mfma_f32_16x16x32_bf16(al1, qbh[kk], S1, 0, 0, 0);
            }

            // ---- exact online softmax in log2 domain ----
            float rm = fmaxf(fmaxf(fmaxf(S0[0], S0[1]), fmaxf(S0[2], S0[3])),
                             fmaxf(fmaxf(S1[0], S1[1]), fmaxf(S1[2], S1[3])));
            rm = fmaxf(rm, __shfl_xor(rm, 16));
            rm = fmaxf(rm, __shfl_xor(rm, 32));
            float mn = fmaxf(mrow, rm * C2);
            float p[8]; float rs = 0.f;
            #pragma unroll
            for (int r = 0; r < 4; ++r) { p[r]   = fexp2(fmaf(S0[r], C2, -mn)); rs += p[r];   }
            #pragma unroll
            for (int r = 0; r < 4; ++r) { p[4+r] = fexp2(fmaf(S1[r], C2, -mn)); rs += p[4+r]; }
            rs += __shfl_xor(rs, 16);
            rs += __shfl_xor(rs, 32);
            float sc = fexp2(mrow - mn);
            lrow = lrow * sc + rs;
            mrow = mn;

            // ---- rescale O accumulator (4 values) ----
            #pragma unroll
            for (int r = 0; r < 4; ++r)
                accv[r] *= __shfl(sc, lg*4 + r);

            // ---- PV: one MFMA; key-map pi(l,e)=16*(e>>2)+lg*4+(e&3) on both ----
            union { short8v v; unsigned u[4]; } pa, vb;
            #pragma unroll
            for (int d = 0; d < 4; ++d) {
                pa.u[d] = cvt_pk_bf16(p[2*d],  p[2*d+1]);
                vb.u[d] = cvt_pk_bf16(vt[2*d], vt[2*d+1]);
            }
            accv = __builtin_amdgcn_mfma_f32_16x16x32_bf16(pa.v, vb.v, accv, 0, 0, 0);
        }
    }

    // ---- write ----
    if (direct) {
        #pragma unroll
        for (int r = 0; r < 4; ++r) {
            float lqr = __shfl(lrow, lg*4 + r);
            out[(size_t)lk * N_PIX + qt0 + lg*4 + r] = accv[r] / lqr;
        }
    } else {
        #pragma unroll
        for (int r = 0; r < 4; ++r)
            macc[((size_t)(s*16 + lk)) * N_PIX + qt0 + lg*4 + r] = accv[r];
        if (lane < 16) {
            mbuf[(size_t)s * N_PIX + qt0 + lane] = mrow;
            lbuf[(size_t)s * N_PIX + qt0 + lane] = lrow;
        }
    }
}

// ---------------------------------------------------------------------------
// Kernel 3: merge split-K partials (m in log2 units).
// ---------------------------------------------------------------------------
__global__ __launch_bounds__(256) void merge_kernel(
    const float* __restrict__ macc, const float* __restrict__ mbuf,
    const float* __restrict__ lbuf, float* __restrict__ out, int S)
{
    int tid = blockIdx.x * 256 + threadIdx.x;   // 0 .. 16*N_PIX-1
    int q = tid & (N_PIX - 1);
    int c = tid >> 14;
    float M = -INFINITY;
    for (int s = 0; s < S; ++s) M = fmaxf(M, mbuf[s*N_PIX + q]);
    float L = 0.f, O = 0.f;
    for (int s = 0; s < S; ++s) {
        float e = fexp2(mbuf[s*N_PIX + q] - M);
        L += lbuf[s*N_PIX + q] * e;
        O += macc[((size_t)(s*16 + c)) * N_PIX + q] * e;
    }
    out[tid] = O / L;
}

// ---------------------------------------------------------------------------
extern "C" void kernel_launch(void* const* d_in, const int* in_sizes, int n_in,
                              void* d_out, int out_size, void* d_ws, size_t ws_size,
                              hipStream_t stream) {
    const float* ego_cls   = (const float*)d_in[0];
    const float* ego_reg   = (const float*)d_in[1];
    const float* other_cls = (const float*)d_in[2];
    const float* other_reg = (const float*)d_in[3];
    const float* w1   = (const float*)d_in[4];
    const float* b1   = (const float*)d_in[5];
    const float* ln_g = (const float*)d_in[6];
    const float* ln_b = (const float*)d_in[7];
    const float* w2   = (const float*)d_in[8];
    const float* b2   = (const float*)d_in[9];

    unsigned short* qhi = (unsigned short*)d_ws;            // 4 MB each
    unsigned short* qlo = qhi + (size_t)N_PIX*EMB;
    unsigned short* khi = qlo + (size_t)N_PIX*EMB;
    unsigned short* klo = khi + (size_t)N_PIX*EMB;
    const size_t planes_bytes = (size_t)4 * N_PIX * EMB * 2;  // 16 MB

    auto need = [&](int S) { return planes_bytes + (size_t)S * N_PIX * 4 * 18; };
    int S = 1, direct = 1;
    if      (ws_size >= need(8)) { S = 8; direct = 0; }
    else if (ws_size >= need(4)) { S = 4; direct = 0; }
    else if (ws_size >= need(2)) { S = 2; direct = 0; }
    int TPS = NTILES / S;
    int XPS = 8 / S;

    float* macc = (float*)((char*)d_ws + planes_bytes);     // [S][16][N]
    float* mbuf = macc + (size_t)S * 16 * N_PIX;            // [S][N]
    float* lbuf = mbuf + (size_t)S * N_PIX;                 // [S][N]

    encode_kernel<<<2*N_PIX, 128, 0, stream>>>(
        ego_cls, ego_reg, other_cls, other_reg,
        w1, b1, ln_g, ln_b, w2, b2, qhi, qlo, khi, klo);

    attn_kernel<<<256*S, 256, 0, stream>>>(
        qhi, qlo, khi, klo, other_cls, other_reg,
        macc, mbuf, lbuf, (float*)d_out, S, TPS, XPS, direct);

    if (!direct)
        merge_kernel<<<(16*N_PIX)/256, 256, 0, stream>>>(
            macc, mbuf, lbuf, (float*)d_out, S);
}